// Round 2
// baseline (276.723 us; speedup 1.0000x reference)
//
#include <hip/hip_runtime.h>
#include <stdint.h>
#include <stddef.h>

// ---------------------------------------------------------------------------
// SelfAttention: out = softmax((x W1^T + b1)(x W2^T + b2)^T) (x W2^T + b2)
// B=4, L=2048, D=1024. DTYPES: inputs fp32, output fp32 (per harness contract:
// reference dtypes are float32). Tolerance is bf16-grade (floor_eps_k=8),
// so internals use fp16 MFMA (2^-11 mantissa, 8x tighter than bf16).
// Pipeline:
//   0. cvt: x,W1,W2 fp32 -> fp16
//   1. proj (f16 MFMA): Q = xW1^T+b1 -> fp16 ; V = xW2^T+b2 -> fp16 (+ Vt)
//   2. score (f16 MFMA): S = Q V^T  -> fp32   [per batch]
//   3. softmax rows (fp32, in-place; writes fp16 P over the fp32 row)
//   4. out (f16 MFMA): out = P Vt^T -> fp32
// GEMM core = m97 structure: 128x128 tile, 4 waves, 4x4 accs of 16x16x32
// MFMA, global_load_lds width=16 staging, 2-barrier K-loop.
// ---------------------------------------------------------------------------

typedef _Float16  f16_t;
typedef _Float16  f16x8  __attribute__((ext_vector_type(8)));
typedef float     f32x4  __attribute__((ext_vector_type(4)));

__device__ __forceinline__ f32x4 mfma16(f16x8 a, f16x8 b, f32x4 c) {
  return __builtin_amdgcn_mfma_f32_16x16x32_f16(a, b, c, 0, 0, 0);
}

__device__ __forceinline__ void async_copy16(const f16_t* g, f16_t* l) {
  // global -> LDS direct DMA, 16B per lane. LDS dest is wave-uniform base +
  // lane*16; our chunk layout (lds byte offset == tid*16) satisfies that.
  __builtin_amdgcn_global_load_lds(
      (const __attribute__((address_space(1))) unsigned int*)(g),
      (__attribute__((address_space(3))) unsigned int*)(l),
      16, 0, 0);
}

// C = A * B^T on a 128x128 tile. A rows at caller offset, K contiguous,
// K = nk*32. acc[i][j] = 16x16 tile in MFMA C-layout (col=lane&15,
// row=quad*4+reg — m89/m91-verified mapping).
__device__ __forceinline__ void gemm_core(
    const f16_t* __restrict__ A, const f16_t* __restrict__ B,
    int lda, int ldb, int nk,
    f16_t* As, f16_t* Bs, f32x4 acc[4][4])
{
  const int tid  = threadIdx.x;
  const int lane = tid & 63;
  const int w    = tid >> 6;
  const int wr   = (w >> 1) * 64;   // wave row offset in tile
  const int wc   = (w & 1) * 64;    // wave col offset in tile
  const int quad = lane >> 4;
  const int l16  = lane & 15;

  // staging: tile is 128 rows x 32 cols; 16B chunk c -> row c>>2, col (c&3)*8
  const int r0  = tid >> 2;
  const int kc0 = (tid & 3) * 8;

  const f16_t* Ag0 = A + (size_t)r0 * lda + kc0;
  const f16_t* Ag1 = A + (size_t)(r0 + 64) * lda + kc0;
  const f16_t* Bg0 = B + (size_t)r0 * ldb + kc0;
  const f16_t* Bg1 = B + (size_t)(r0 + 64) * ldb + kc0;
  f16_t* Al0 = As + tid * 8;
  f16_t* Al1 = As + (tid + 256) * 8;
  f16_t* Bl0 = Bs + tid * 8;
  f16_t* Bl1 = Bs + (tid + 256) * 8;

  for (int kt = 0; kt < nk; ++kt) {
    async_copy16(Ag0, Al0);
    async_copy16(Ag1, Al1);
    async_copy16(Bg0, Bl0);
    async_copy16(Bg1, Bl1);
    __syncthreads();   // compiler drains vmcnt(0) before s_barrier (m97)

    f16x8 af[4], bfr[4];
#pragma unroll
    for (int i = 0; i < 4; ++i) {
      af[i]  = *(const f16x8*)(As + (wr + i * 16 + l16) * 32 + quad * 8);
      bfr[i] = *(const f16x8*)(Bs + (wc + i * 16 + l16) * 32 + quad * 8);
    }
#pragma unroll
    for (int i = 0; i < 4; ++i)
#pragma unroll
      for (int j = 0; j < 4; ++j)
        acc[i][j] = mfma16(af[i], bfr[j], acc[i][j]);

    __syncthreads();   // protect LDS before next stage overwrites
    Ag0 += 32; Ag1 += 32; Bg0 += 32; Bg1 += 32;
  }
}

// ---------------------------------------------------------------------------
// 0) fp32 -> fp16 converter, 8 elems/thread, fully vectorized.
__global__ __launch_bounds__(256) void cvt_kernel(
    const float* __restrict__ in, f16_t* __restrict__ out)
{
  const size_t i = ((size_t)blockIdx.x * 256 + threadIdx.x) * 8;
  f32x4 a = *(const f32x4*)(in + i);
  f32x4 b = *(const f32x4*)(in + i + 4);
  f16x8 o;
#pragma unroll
  for (int k = 0; k < 4; ++k) { o[k] = (f16_t)a[k]; o[k + 4] = (f16_t)b[k]; }
  *(f16x8*)(out + i) = o;
}

// ---------------------------------------------------------------------------
// 1) projection: Out[row, col] = sum_d X[row,d] * W[col,d] + bias[col]
//    X: [8192,1024] f16, W: [1024,1024] f16 -> Out fp16 [8192,1024]
//    If OutT != null also write OutT[batch][col][key] (transposed V).
__global__ __launch_bounds__(256) void proj_kernel(
    const f16_t* __restrict__ X, const f16_t* __restrict__ W,
    const float* __restrict__ bias, f16_t* __restrict__ Out,
    f16_t* __restrict__ OutT)
{
  __shared__ __align__(16) f16_t As[128 * 32];
  __shared__ __align__(16) f16_t Bs[128 * 32];
  const int m0 = blockIdx.x * 128;
  const int n0 = blockIdx.y * 128;

  f32x4 acc[4][4] = {};
  gemm_core(X + (size_t)m0 * 1024, W + (size_t)n0 * 1024,
            1024, 1024, 1024 / 32, As, Bs, acc);

  const int lane = threadIdx.x & 63;
  const int w    = threadIdx.x >> 6;
  const int wr   = (w >> 1) * 64, wc = (w & 1) * 64;
  const int quad = lane >> 4,     l16 = lane & 15;

#pragma unroll
  for (int j = 0; j < 4; ++j) {
    const int col = n0 + wc + j * 16 + l16;
    const float bj = bias[col];
#pragma unroll
    for (int i = 0; i < 4; ++i) {
#pragma unroll
      for (int r = 0; r < 4; ++r) {
        const int row = m0 + wr + i * 16 + quad * 4 + r;  // C: row=quad*4+r
        const float v = acc[i][j][r] + bj;
        Out[(size_t)row * 1024 + col] = (f16_t)v;
        if (OutT) {
          const int b = row >> 11, key = row & 2047;
          OutT[(((size_t)b << 10) + col) * 2048 + key] = (f16_t)v;
        }
      }
    }
  }
}

// ---------------------------------------------------------------------------
// 2) scores: S[b][q][k] = Q[b,q,:] . V[b,k,:]   (fp32 out, 64 MiB)
__global__ __launch_bounds__(256) void score_kernel(
    const f16_t* __restrict__ Q, const f16_t* __restrict__ V,
    float* __restrict__ S)
{
  __shared__ __align__(16) f16_t As[128 * 32];
  __shared__ __align__(16) f16_t Bs[128 * 32];
  const int m0 = blockIdx.x * 128;
  const int n0 = blockIdx.y * 128;
  const size_t boff = (size_t)blockIdx.z * 2048 * 1024;

  f32x4 acc[4][4] = {};
  gemm_core(Q + boff + (size_t)m0 * 1024, V + boff + (size_t)n0 * 1024,
            1024, 1024, 1024 / 32, As, Bs, acc);

  float* Sb = S + (size_t)blockIdx.z * 2048 * 2048;
  const int lane = threadIdx.x & 63;
  const int w    = threadIdx.x >> 6;
  const int wr   = (w >> 1) * 64, wc = (w & 1) * 64;
  const int quad = lane >> 4,     l16 = lane & 15;

#pragma unroll
  for (int i = 0; i < 4; ++i)
#pragma unroll
    for (int j = 0; j < 4; ++j)
#pragma unroll
      for (int r = 0; r < 4; ++r) {
        const int row = m0 + wr + i * 16 + quad * 4 + r;
        const int col = n0 + wc + j * 16 + l16;
        Sb[(size_t)row * 2048 + col] = acc[i][j][r];
      }
}

// ---------------------------------------------------------------------------
// 3) softmax over each row of S (2048 fp32), write fp16 P in-place over the
//    row's first 4096 bytes. One block per row; block owns its row; all row
//    reads happen before the barriers that precede the overlapping writes.
__global__ __launch_bounds__(256) void softmax_kernel(float* __restrict__ S)
{
  float* src = S + (size_t)blockIdx.x * 2048;
  f16_t* dst = (f16_t*)src;
  const int tid  = threadIdx.x;
  const int lane = tid & 63;
  const int w    = tid >> 6;

  f32x4 va = *((const f32x4*)src + tid * 2);
  f32x4 vb = *((const f32x4*)src + tid * 2 + 1);
  float f[8];
#pragma unroll
  for (int k = 0; k < 4; ++k) { f[k] = va[k]; f[k + 4] = vb[k]; }

  float m = f[0];
#pragma unroll
  for (int k = 1; k < 8; ++k) m = fmaxf(m, f[k]);
#pragma unroll
  for (int off = 32; off >= 1; off >>= 1) m = fmaxf(m, __shfl_xor(m, off));

  __shared__ float red[4];
  if (lane == 0) red[w] = m;
  __syncthreads();
  m = fmaxf(fmaxf(red[0], red[1]), fmaxf(red[2], red[3]));

  float s = 0.f;
#pragma unroll
  for (int k = 0; k < 8; ++k) { f[k] = __expf(f[k] - m); s += f[k]; }
#pragma unroll
  for (int off = 32; off >= 1; off >>= 1) s += __shfl_xor(s, off);
  __syncthreads();             // everyone done reading red (and src)
  if (lane == 0) red[w] = s;
  __syncthreads();
  s = (red[0] + red[1]) + (red[2] + red[3]);
  const float inv = 1.f / s;

  f16x8 o;
#pragma unroll
  for (int k = 0; k < 8; ++k) o[k] = (f16_t)(f[k] * inv);
  *((f16x8*)dst + tid) = o;    // after barriers: all row reads complete
}

// ---------------------------------------------------------------------------
// 4) out[b][q][d] = sum_k P[b][q][k] * Vt[b][d][k]  -> fp32
//    P pitch = 4096 f16 (fp16 packed at start of each fp32 row of S).
__global__ __launch_bounds__(256) void out_kernel(
    const f16_t* __restrict__ P, const f16_t* __restrict__ Vt,
    float* __restrict__ Out)
{
  __shared__ __align__(16) f16_t As[128 * 32];
  __shared__ __align__(16) f16_t Bs[128 * 32];
  const int m0 = blockIdx.x * 128;
  const int n0 = blockIdx.y * 128;
  const size_t poff  = (size_t)blockIdx.z * 2048 * 4096;  // f16 elements
  const size_t vtoff = (size_t)blockIdx.z * 1024 * 2048;

  f32x4 acc[4][4] = {};
  gemm_core(P + poff + (size_t)m0 * 4096, Vt + vtoff + (size_t)n0 * 2048,
            4096, 2048, 2048 / 32, As, Bs, acc);

  float* Ob = Out + (size_t)blockIdx.z * 2048 * 1024;
  const int lane = threadIdx.x & 63;
  const int w    = threadIdx.x >> 6;
  const int wr   = (w >> 1) * 64, wc = (w & 1) * 64;
  const int quad = lane >> 4,     l16 = lane & 15;

#pragma unroll
  for (int i = 0; i < 4; ++i)
#pragma unroll
    for (int j = 0; j < 4; ++j)
#pragma unroll
      for (int r = 0; r < 4; ++r) {
        const int row = m0 + wr + i * 16 + quad * 4 + r;
        const int col = n0 + wc + j * 16 + l16;
        Ob[(size_t)row * 1024 + col] = acc[i][j][r];
      }
}

// ---------------------------------------------------------------------------
extern "C" void kernel_launch(void* const* d_in, const int* in_sizes, int n_in,
                              void* d_out, int out_size, void* d_ws, size_t ws_size,
                              hipStream_t stream) {
  const float* x  = (const float*)d_in[0];
  const float* W1 = (const float*)d_in[1];
  const float* b1 = (const float*)d_in[2];
  const float* W2 = (const float*)d_in[3];
  const float* b2 = (const float*)d_in[4];
  float* out = (float*)d_out;

  // workspace layout (~132 MiB):
  const size_t QN = (size_t)8192 * 1024;   // 8.39M elements
  const size_t WN = (size_t)1024 * 1024;
  f16_t* xh  = (f16_t*)d_ws;       // 16 MiB fp16 [8192,1024]
  f16_t* W1h = xh + QN;            //  2 MiB fp16 [1024,1024]
  f16_t* W2h = W1h + WN;           //  2 MiB
  f16_t* Q   = W2h + WN;           // 16 MiB fp16 [8192,1024]
  f16_t* V   = Q + QN;             // 16 MiB fp16 [8192,1024]
  f16_t* Vt  = V + QN;             // 16 MiB fp16 [4][1024][2048]
  float* S   = (float*)(Vt + QN);  // 64 MiB fp32 [4][2048][2048] (P in-place)

  dim3 blk(256);
  cvt_kernel<<<4096, blk, 0, stream>>>(x, xh);
  cvt_kernel<<<512, blk, 0, stream>>>(W1, W1h);
  cvt_kernel<<<512, blk, 0, stream>>>(W2, W2h);
  proj_kernel<<<dim3(64, 8), blk, 0, stream>>>(xh, W1h, b1, Q, nullptr);
  proj_kernel<<<dim3(64, 8), blk, 0, stream>>>(xh, W2h, b2, V, Vt);
  score_kernel<<<dim3(16, 16, 4), blk, 0, stream>>>(Q, V, S);
  softmax_kernel<<<8192, blk, 0, stream>>>(S);
  out_kernel<<<dim3(16, 8, 4), blk, 0, stream>>>((const f16_t*)S, Vt, out);
}